// Round 1
// baseline (695.282 us; speedup 1.0000x reference)
//
#include <hip/hip_runtime.h>

// segment_sum: out[receivers[e], :] += edges[e, :]
// E=1,600,000 edges, D_EDGE=50, N_NODES=100,000, fp32.
// Inputs (setup_inputs order): nodes (unused for values), edges, receivers.

#define N_EDGES   1600000
#define D_EDGE    50
#define N_NODES   100000
#define TOTAL_EL  (N_EDGES * D_EDGE)   // 80,000,000 elements

__global__ __launch_bounds__(256) void scatter_add_kernel(
    const float* __restrict__ edges,
    const int*   __restrict__ receivers,
    float*       __restrict__ out)
{
    long long t = (long long)blockIdx.x * blockDim.x + threadIdx.x;
    if (t >= (long long)TOTAL_EL) return;
    int e = (int)(t / D_EDGE);
    int d = (int)(t - (long long)e * D_EDGE);
    int r = receivers[e];
    atomicAdd(&out[(long long)r * D_EDGE + d], edges[t]);
}

extern "C" void kernel_launch(void* const* d_in, const int* in_sizes, int n_in,
                              void* d_out, int out_size, void* d_ws, size_t ws_size,
                              hipStream_t stream) {
    // d_in[0] = nodes (float32, 100000x8)  -- values unused, only defines N_NODES
    // d_in[1] = edges (float32, 1600000x50)
    // d_in[2] = receivers (int32, 1600000)
    const float* edges     = (const float*)d_in[1];
    const int*   receivers = (const int*)d_in[2];
    float*       out       = (float*)d_out;

    // Output is re-poisoned to 0xAA before every timed call: zero it first.
    hipMemsetAsync(d_out, 0, (size_t)out_size * sizeof(float), stream);

    const int block = 256;
    const int grid  = (TOTAL_EL + block - 1) / block;
    scatter_add_kernel<<<grid, block, 0, stream>>>(edges, receivers, out);
}